// Round 11
// baseline (26.294 us; speedup 1.0000x reference)
//
#include <hip/hip_runtime.h>

typedef _Float16 half2_t __attribute__((ext_vector_type(2)));
typedef float float4_t __attribute__((ext_vector_type(4)));

#define NN 2048
#define DD 32
#define HH 64
#define HP 32            // half2 pairs along h
#define SCALE 0.0625f    // store (A+b1)/16, B/16 (headroom; relu via pk_max)
#define ISCALE 16.0f     // folded back into w2

// ---------------------------------------------------------------------------
// Kernel 1 (unchanged): A'[n][h] = Z@W1[:D] + b1 ; B = Z@W1[D:]
// Stored transposed, h-pair packed f16, scaled by 1/16: At[hp][n]
// ---------------------------------------------------------------------------
__global__ __launch_bounds__(256) void precompute_kernel(
    const float* __restrict__ Z, const float* __restrict__ W1,
    const float* __restrict__ b1, unsigned* __restrict__ At,
    unsigned* __restrict__ Bt)
{
  __shared__ float zt[32][DD];       // 4 KB
  __shared__ unsigned st[HP][33];    // padded transpose bounce
  const int t   = threadIdx.x;
  const int isB = blockIdx.y;
  const int n0  = blockIdx.x * 32;

#pragma unroll
  for (int k = 0; k < 4; ++k) {
    const int idx = t + k * 256;
    zt[idx >> 5][idx & 31] = Z[(n0 + (idx >> 5)) * DD + (idx & 31)];
  }
  __syncthreads();

  const int hp = t & 31;
  const int nb = (t >> 5) * 4;       // 4 rows per thread
  const float* w = W1 + (isB ? DD * HH : 0);
  const float c0 = isB ? 0.f : b1[2 * hp];
  const float c1 = isB ? 0.f : b1[2 * hp + 1];

  float acc0[4], acc1[4];
#pragma unroll
  for (int k = 0; k < 4; ++k) { acc0[k] = c0; acc1[k] = c1; }

  for (int d = 0; d < DD; ++d) {
    const float w0 = w[d * HH + 2 * hp];
    const float w1 = w[d * HH + 2 * hp + 1];
#pragma unroll
    for (int k = 0; k < 4; ++k) {
      const float z = zt[nb + k][d];
      acc0[k] = fmaf(z, w0, acc0[k]);
      acc1[k] = fmaf(z, w1, acc1[k]);
    }
  }

#pragma unroll
  for (int k = 0; k < 4; ++k) {
    half2_t h;
    h.x = (_Float16)(acc0[k] * SCALE);
    h.y = (_Float16)(acc1[k] * SCALE);
    st[hp][nb + k] = __builtin_bit_cast(unsigned, h);
  }
  __syncthreads();

  unsigned* outp = isB ? Bt : At;
#pragma unroll
  for (int k = 0; k < 4; ++k) {
    const int idx = t + k * 256;          // 32x32 u32 tile
    const int r = idx >> 5, c = idx & 31;
    outp[r * NN + n0 + c] = st[r][c];
  }
}

// ---------------------------------------------------------------------------
// Kernel 2: 64x64 tile, 256 threads, per-thread 4x4, 4 blocks/CU.
// KEY CHANGES vs R9:
//  (1) 4-hp batched LDS reads: issue 8 ds_read_b128 into forward-only
//      locals, THEN compute 4 hp worth of VALU -> one lgkmcnt wait per
//      ~384 compute cycles instead of per 64 (hides LDS latency).
//  (2) zero inline asm in the loop (pk_add+pk_max builtins) so LLVM's
//      scheduler is free to interleave — the 512 asm statements were a
//      suspected scheduling inhibitor AND the R3/R4/R10 rotation shape
//      is a confirmed hipcc compile-time pathology (3/3 timeouts).
// ---------------------------------------------------------------------------
__global__ __launch_bounds__(256, 4) void decoder_main(
    const unsigned* __restrict__ At, const unsigned* __restrict__ Bt,
    const float* __restrict__ W2, const float* __restrict__ b2,
    float* __restrict__ out)
{
  __shared__ unsigned Al[HP][64];    // 8 KB
  __shared__ unsigned Bl[HP][64];    // 8 KB

  const int t  = threadIdx.x;
  const int i0 = blockIdx.y * 64;
  const int j0 = blockIdx.x * 64;

  // stage both 32x64 u32 tiles: uint4 per thread, coalesced
  {
    const int c4 = (t & 15) * 4;          // 4 consecutive n per thread
    const int hb = t >> 4;                // 0..15
#pragma unroll
    for (int k = 0; k < 2; ++k) {
      const int hp = hb + k * 16;
      *reinterpret_cast<uint4*>(&Al[hp][c4]) =
          *reinterpret_cast<const uint4*>(&At[hp * NN + i0 + c4]);
      *reinterpret_cast<uint4*>(&Bl[hp][c4]) =
          *reinterpret_cast<const uint4*>(&Bt[hp * NN + j0 + c4]);
    }
  }

  // w2 (x16) packed to half2 -> SGPRs via readfirstlane (wave-uniform)
  unsigned w2u[HP];
#pragma unroll
  for (int p = 0; p < HP; ++p) {
    half2_t h;
    h.x = (_Float16)(W2[2 * p] * ISCALE);
    h.y = (_Float16)(W2[2 * p + 1] * ISCALE);
    w2u[p] = __builtin_amdgcn_readfirstlane(__builtin_bit_cast(unsigned, h));
  }
  __syncthreads();

  const int tx = t & 15, ty = t >> 4;   // tx -> j (4 cols), ty -> i (4 rows)

  float acc[4][4];
#pragma unroll
  for (int r = 0; r < 4; ++r)
#pragma unroll
    for (int c = 0; c < 4; ++c) acc[r][c] = 0.f;

  const half2_t zero = {(_Float16)0.f, (_Float16)0.f};

#pragma unroll
  for (int g = 0; g < 8; ++g) {
    // ---- batch-issue 8 LDS reads for hp = 4g .. 4g+3 (forward-only) ----
    uint4 av[4], bv[4];
#pragma unroll
    for (int q = 0; q < 4; ++q) {
      av[q] = *reinterpret_cast<const uint4*>(&Al[4 * g + q][ty * 4]);
      bv[q] = *reinterpret_cast<const uint4*>(&Bl[4 * g + q][tx * 4]);
    }
    // ---- compute 4 hp ----
#pragma unroll
    for (int q = 0; q < 4; ++q) {
      half2_t a[4], b[4];
      a[0] = __builtin_bit_cast(half2_t, av[q].x);
      a[1] = __builtin_bit_cast(half2_t, av[q].y);
      a[2] = __builtin_bit_cast(half2_t, av[q].z);
      a[3] = __builtin_bit_cast(half2_t, av[q].w);
      b[0] = __builtin_bit_cast(half2_t, bv[q].x);
      b[1] = __builtin_bit_cast(half2_t, bv[q].y);
      b[2] = __builtin_bit_cast(half2_t, bv[q].z);
      b[3] = __builtin_bit_cast(half2_t, bv[q].w);

      const half2_t w2v = __builtin_bit_cast(half2_t, w2u[4 * g + q]);
#pragma unroll
      for (int r = 0; r < 4; ++r)
#pragma unroll
        for (int c = 0; c < 4; ++c) {
          half2_t s = a[r] + b[c];                     // v_pk_add_f16
          s = __builtin_elementwise_max(s, zero);      // v_pk_max_f16 (relu)
          acc[r][c] = __builtin_amdgcn_fdot2(s, w2v, acc[r][c], false);
        }
    }
  }

  const float b2v = b2[0];
  const float NLOG2E = -1.44269504f;
#pragma unroll
  for (int r = 0; r < 4; ++r) {
    float y[4];
#pragma unroll
    for (int c = 0; c < 4; ++c) {
      const float x = acc[r][c] + b2v;
      const float e = __builtin_amdgcn_exp2f(x * NLOG2E);   // e^{-x}
      y[c] = __builtin_amdgcn_rcpf(1.0f + e);               // sigmoid
    }
    float* o = out + (size_t)(i0 + ty * 4 + r) * NN + j0 + tx * 4;
    float4_t v = {y[0], y[1], y[2], y[3]};
    *reinterpret_cast<float4_t*>(o) = v;
  }
}

extern "C" void kernel_launch(void* const* d_in, const int* in_sizes, int n_in,
                              void* d_out, int out_size, void* d_ws, size_t ws_size,
                              hipStream_t stream) {
  const float* Z  = (const float*)d_in[0];
  const float* W1 = (const float*)d_in[1];
  const float* b1 = (const float*)d_in[2];
  const float* W2 = (const float*)d_in[3];
  const float* b2 = (const float*)d_in[4];
  float* out = (float*)d_out;

  unsigned* At = (unsigned*)d_ws;          // 32*2048 u32 = 256 KB
  unsigned* Bt = At + HP * NN;             // 256 KB

  dim3 pgrid(NN / 32, 2);                  // 128 blocks
  precompute_kernel<<<pgrid, 256, 0, stream>>>(Z, W1, b1, At, Bt);

  dim3 mgrid(NN / 64, NN / 64);            // 32 x 32 = 1024 blocks
  decoder_main<<<mgrid, 256, 0, stream>>>(At, Bt, W2, b2, out);
}